// Round 10
// baseline (162.335 us; speedup 1.0000x reference)
//
#include <hip/hip_runtime.h>
#include <hip/hip_bf16.h>
#include <math.h>

#define N_PTS 50000
#define CCH   64
#define KP    15
#define NH    32
#define SIGMA 0.7f
#define BN_EPS 1e-5f
#define LEAKY 0.1f
#define QB    16
#define CWS   18           // cwT row stride in bf16 (16 q + 2 pad -> 2-way banks, free)
#define STATS_BLOCKS 1024
#define W2P_BLOCKS   30
#define QC           64    // queries per classification block
#define CLS_BLOCKS   782   // ceil(50000/64)

typedef short bf16x8 __attribute__((ext_vector_type(8)));
typedef float floatx4 __attribute__((ext_vector_type(4)));

__device__ __forceinline__ unsigned short f2b(float f) {
    union { float f; unsigned u; } v; v.f = f;
    return (unsigned short)((v.u + 0x7FFFu + ((v.u >> 16) & 1u)) >> 16);  // RNE
}
__device__ __forceinline__ ushort2 f2b2(float a, float b) {   // v_cvt_pk_bf16_f32
    __hip_bfloat162 h = __float22bfloat162_rn(float2{a, b});
    union { __hip_bfloat162 h; ushort2 u; } v; v.h = h;
    return v.u;
}
__device__ __forceinline__ float b2f(unsigned short b) {
    union { unsigned u; float f; } v; v.u = ((unsigned)b) << 16;
    return v.f;
}

// ---------- K1: [0,1024) stats: h = sf@W1 -> hst bf16 + BN sums + sfb shadow.
//             [1024,1054) W2 repack.  [1054,1836) neighbor classification. ----------
__global__ __launch_bounds__(256) void k_prep(const float* __restrict__ sf,
                                              const float* __restrict__ W1,
                                              const float* __restrict__ W2,
                                              const float* __restrict__ q_pts,
                                              const float* __restrict__ s_pts,
                                              const int* __restrict__ nb,
                                              const float* __restrict__ kpts,
                                              float* __restrict__ bn,
                                              unsigned short* __restrict__ hst,
                                              unsigned short* __restrict__ w2b,
                                              unsigned short* __restrict__ sfb,
                                              unsigned* __restrict__ packG,
                                              int* __restrict__ cntG) {
    int t = threadIdx.x;
    if (blockIdx.x >= STATS_BLOCKS + W2P_BLOCKS) {
        // ---- neighbor classification: 1-NN kernel point + influence, compacted ----
        int q0 = (blockIdx.x - (STATS_BLOCKS + W2P_BLOCKS)) * QC;
        __shared__ int cnt[QC];
        for (int i = t; i < QC; i += 256) cnt[i] = 0;
        float kpr[45];
        #pragma unroll
        for (int i = 0; i < 45; ++i) kpr[i] = kpts[i];   // uniform -> s_loads
        __syncthreads();
        for (int task = t; task < QC * NH; task += 256) {
            int ql = task >> 5, hh = task & 31;
            int m = q0 + ql;
            if (m >= N_PTS) continue;
            int idx = nb[m * NH + hh];
            float px = s_pts[idx * 3 + 0] - q_pts[m * 3 + 0];
            float py = s_pts[idx * 3 + 1] - q_pts[m * 3 + 1];
            float pz = s_pts[idx * 3 + 2] - q_pts[m * 3 + 2];
            float best = 1e30f; int bi = 0;
            #pragma unroll
            for (int k = 0; k < KP; ++k) {
                float dx = px - kpr[k*3], dy = py - kpr[k*3+1], dz = pz - kpr[k*3+2];
                float d = dx * dx + dy * dy + dz * dz;
                if (d < best) { best = d; bi = k; }
            }
            float infl = 1.f - sqrtf(best) * (1.0f / SIGMA);
            if (infl > 0.f) {
                int iq = (int)(infl * 4095.f + 0.5f);
                int pos = atomicAdd(&cnt[ql], 1);
                packG[m * NH + pos] = (unsigned)idx | ((unsigned)bi << 16)
                                    | ((unsigned)iq << 20);
            }
        }
        __syncthreads();
        // zero-fill unused slots (garbage-safe 4-wide reads in k_main) + counts
        for (int i = t; i < QC * NH; i += 256) {
            int ql = i >> 5, j = i & 31;
            int m = q0 + ql;
            if (m >= N_PTS) continue;
            if (j >= cnt[ql]) packG[m * NH + j] = 0u;
            if (j == 0) cntG[m] = cnt[ql];
        }
        return;
    }
    if (blockIdx.x >= STATS_BLOCKS) {
        // w2b[((tile*2+kstep)*64+lane)*8+j] = bf16(W2[k][n]),
        //   k = kstep*32 + (lane>>4)*8 + j, n = tile*16 + (lane&15)
        int g = (blockIdx.x - STATS_BLOCKS) * 256 + t;   // 7680 exactly
        int lane = g & 63, s = (g >> 6) & 1, tt = g >> 7;
        int col = lane & 15, quad = lane >> 4;
        int base = (s * 32 + quad * 8) * 960 + tt * 16 + col;
        ushort4 lo, hi;
        lo.x = f2b(W2[base + 0 * 960]); lo.y = f2b(W2[base + 1 * 960]);
        lo.z = f2b(W2[base + 2 * 960]); lo.w = f2b(W2[base + 3 * 960]);
        hi.x = f2b(W2[base + 4 * 960]); hi.y = f2b(W2[base + 5 * 960]);
        hi.z = f2b(W2[base + 6 * 960]); hi.w = f2b(W2[base + 7 * 960]);
        *(ushort4*)(w2b + g * 8)     = lo;
        *(ushort4*)(w2b + g * 8 + 4) = hi;
        return;
    }
    int c = t & 63, ml = t >> 6;
    float w1c[64];
    #pragma unroll
    for (int i = 0; i < 64; ++i) w1c[i] = W1[i * 64 + c];
    __shared__ float rows[4][64];
    float acc_s = 0.f, acc_q = 0.f;
    for (int m0 = blockIdx.x * 4; m0 < N_PTS; m0 += STATS_BLOCKS * 4) {
        __syncthreads();
        float v = sf[m0 * 64 + t];
        ((float*)rows)[t] = v;
        sfb[m0 * 64 + t] = f2b(v);             // bf16 shadow for phase-B gathers
        __syncthreads();
        float h = 0.f;
        #pragma unroll
        for (int i4 = 0; i4 < 16; ++i4) {
            float4 r = *(const float4*)&rows[ml][i4 * 4];
            h += r.x * w1c[i4 * 4] + r.y * w1c[i4 * 4 + 1]
               + r.z * w1c[i4 * 4 + 2] + r.w * w1c[i4 * 4 + 3];
        }
        acc_s += h;
        acc_q += h * h;
        hst[(m0 + ml) * 64 + c] = f2b(h);      // 128B/wave coalesced
    }
    __shared__ float red[2][256];
    red[0][t] = acc_s; red[1][t] = acc_q;
    __syncthreads();
    if (t < 64) {
        float s = red[0][t] + red[0][64 + t] + red[0][128 + t] + red[0][192 + t];
        float q = red[1][t] + red[1][64 + t] + red[1][128 + t] + red[1][192 + t];
        atomicAdd(&bn[t], s);
        atomicAdd(&bn[64 + t], q);
    }
}

// ---------- K2: fused main. 256 threads / 4 waves — the proven round-3 shape. ----------
__global__ __launch_bounds__(256, 4) void k_main(
    const unsigned short* __restrict__ sfb,
    const float* __restrict__ gamma, const float* __restrict__ beta,
    const float* __restrict__ bn, const float* __restrict__ b2,
    const unsigned short* __restrict__ w2b, const unsigned short* __restrict__ hst,
    const unsigned* __restrict__ packG, const int* __restrict__ cntG,
    float* __restrict__ out) {

    __shared__ __align__(16) unsigned short cwT[960 * CWS];  // 34.56 KB: cw[n][q] bf16
    __shared__ float abS[128];                               // BN fold a[64], b[64]

    int t = threadIdx.x;
    int lane = t & 63, wv = t >> 6;
    int m0 = blockIdx.x * QB;

    if (t < 64) {   // inline BN finalize
        float mu  = bn[t] * (1.0f / N_PTS);
        float var = bn[64 + t] * (1.0f / N_PTS) - mu * mu;
        float a   = gamma[t] * rsqrtf(var + BN_EPS);
        abS[t]      = a;
        abS[64 + t] = beta[t] - mu * a;
    }
    __syncthreads();

    // ---- A-fragments directly in registers: fold BN + leaky on bf16 h rows ----
    int row = lane & 15, half = lane >> 4;
    bf16x8 a0, a1;
    {
        const unsigned short* hrow = hst + (m0 + row) * 64 + half * 8;
        bf16x8 r0 = *(const bf16x8*)(hrow);        // c = half*8 + j
        bf16x8 r1 = *(const bf16x8*)(hrow + 32);   // c = 32 + half*8 + j
        #pragma unroll
        for (int j = 0; j < 8; j += 2) {
            int c0 = half * 8 + j;
            float g0 = abS[c0] * b2f((unsigned short)r0[j]) + abS[64 + c0];
            float g1 = abS[c0 + 1] * b2f((unsigned short)r0[j + 1]) + abS[64 + c0 + 1];
            g0 = g0 > 0.f ? g0 : LEAKY * g0;
            g1 = g1 > 0.f ? g1 : LEAKY * g1;
            ushort2 p01 = f2b2(g0, g1);
            a0[j] = (short)p01.x; a0[j + 1] = (short)p01.y;
            int c1 = 32 + c0;
            float g2 = abS[c1] * b2f((unsigned short)r1[j]) + abS[64 + c1];
            float g3 = abS[c1 + 1] * b2f((unsigned short)r1[j + 1]) + abS[64 + c1 + 1];
            g2 = g2 > 0.f ? g2 : LEAKY * g2;
            g3 = g3 > 0.f ? g3 : LEAKY * g3;
            ushort2 p23 = f2b2(g2, g3);
            a1[j] = (short)p23.x; a1[j + 1] = (short)p23.y;
        }
    }

    // ---- phase A: cw = G @ W2 via MFMA; each wave owns 15 n-tiles ----
    {
        int col = lane & 15, quad = lane >> 4;
        for (int ti = 0; ti < 15; ++ti) {
            int tt = wv * 15 + ti;
            bf16x8 bf0 = *(const bf16x8*)(w2b + ((tt * 2 + 0) * 64 + lane) * 8);
            bf16x8 bf1 = *(const bf16x8*)(w2b + ((tt * 2 + 1) * 64 + lane) * 8);
            floatx4 acc = {0.f, 0.f, 0.f, 0.f};
            acc = __builtin_amdgcn_mfma_f32_16x16x32_bf16(a0, bf0, acc, 0, 0, 0);
            acc = __builtin_amdgcn_mfma_f32_16x16x32_bf16(a1, bf1, acc, 0, 0, 0);
            int n = tt * 16 + col;
            float bb = b2[n];
            unsigned short* dst = &cwT[n * CWS + quad * 4];   // D: row(q)=quad*4+reg
            ushort2 w01 = f2b2(acc[0] + bb, acc[1] + bb);     // v_cvt_pk_bf16_f32
            ushort2 w23 = f2b2(acc[2] + bb, acc[3] + bb);
            *(ushort2*)(dst)     = w01;
            *(ushort2*)(dst + 2) = w23;
        }
    }
    __syncthreads();

    // ---- phase B: wave owns 4 queries as 2 pairs; 4-wide interleave.
    //      List reads are wave-uniform (readfirstlane) -> scalar s_loads. ----
    {
        int wvu = __builtin_amdgcn_readfirstlane(wv);
        int c = lane;
        #pragma unroll
        for (int pp = 0; pp < 2; ++pp) {
            int qa = wvu * 4 + pp * 2, qb = qa + 1;
            int ma = m0 + qa, mb = m0 + qb;
            const unsigned* pA = packG + ma * NH;
            const unsigned* pB = packG + mb * NH;
            const unsigned short* cwa = cwT + c * CWS + qa;   // per-lane cw base
            const unsigned short* cwb = cwa + 1;
            int cA = cntG[ma], cB = cntG[mb];                 // uniform -> s_load
            int na = cA > cB ? cA : cB;
            na = (na + 3) & ~3;                               // slots < 32 are zeroed
            float accA = 0.f, accB = 0.f;
            for (int jj = 0; jj < na; jj += 4) {
                unsigned pa0 = pA[jj], pa1 = pA[jj+1], pa2 = pA[jj+2], pa3 = pA[jj+3];
                unsigned pb0 = pB[jj], pb1 = pB[jj+1], pb2 = pB[jj+2], pb3 = pB[jj+3];
                // 8 independent bf16 gathers
                float fA0 = b2f(sfb[(pa0 & 0xFFFFu) * 64 + c]);
                float fA1 = b2f(sfb[(pa1 & 0xFFFFu) * 64 + c]);
                float fA2 = b2f(sfb[(pa2 & 0xFFFFu) * 64 + c]);
                float fA3 = b2f(sfb[(pa3 & 0xFFFFu) * 64 + c]);
                float fB0 = b2f(sfb[(pb0 & 0xFFFFu) * 64 + c]);
                float fB1 = b2f(sfb[(pb1 & 0xFFFFu) * 64 + c]);
                float fB2 = b2f(sfb[(pb2 & 0xFFFFu) * 64 + c]);
                float fB3 = b2f(sfb[(pb3 & 0xFFFFu) * 64 + c]);
                // 8 LDS reads (k*64*CWS offset from scalar field)
                float wA0 = b2f(cwa[((pa0 >> 16) & 15u) * (64 * CWS)]);
                float wA1 = b2f(cwa[((pa1 >> 16) & 15u) * (64 * CWS)]);
                float wA2 = b2f(cwa[((pa2 >> 16) & 15u) * (64 * CWS)]);
                float wA3 = b2f(cwa[((pa3 >> 16) & 15u) * (64 * CWS)]);
                float wB0 = b2f(cwb[((pb0 >> 16) & 15u) * (64 * CWS)]);
                float wB1 = b2f(cwb[((pb1 >> 16) & 15u) * (64 * CWS)]);
                float wB2 = b2f(cwb[((pb2 >> 16) & 15u) * (64 * CWS)]);
                float wB3 = b2f(cwb[((pb3 >> 16) & 15u) * (64 * CWS)]);
                // q12 influence from scalar field
                float iA0 = (float)(pa0 >> 20), iA1 = (float)(pa1 >> 20);
                float iA2 = (float)(pa2 >> 20), iA3 = (float)(pa3 >> 20);
                float iB0 = (float)(pb0 >> 20), iB1 = (float)(pb1 >> 20);
                float iB2 = (float)(pb2 >> 20), iB3 = (float)(pb3 >> 20);
                accA += iA0 * fA0 * wA0 + iA1 * fA1 * wA1
                      + iA2 * fA2 * wA2 + iA3 * fA3 * wA3;
                accB += iB0 * fB0 * wB0 + iB1 * fB1 * wB1
                      + iB2 * fB2 * wB2 + iB3 * fB3 * wB3;
            }
            const float qs = 1.f / 4095.f;
            out[ma * 64 + c] = accA * qs;
            out[mb * 64 + c] = accB * qs;
        }
    }
}

extern "C" void kernel_launch(void* const* d_in, const int* in_sizes, int n_in,
                              void* d_out, int out_size, void* d_ws, size_t ws_size,
                              hipStream_t stream) {
    const float* q_pts   = (const float*)d_in[0];
    const float* s_pts   = (const float*)d_in[1];
    const float* s_feats = (const float*)d_in[2];
    const int*   nb      = (const int*)d_in[3];
    const float* kpts    = (const float*)d_in[4];
    const float* W1      = (const float*)d_in[5];
    const float* gamma   = (const float*)d_in[6];
    const float* beta    = (const float*)d_in[7];
    const float* W2      = (const float*)d_in[8];
    const float* b2      = (const float*)d_in[9];
    float* out = (float*)d_out;

    float* ws = (float*)d_ws;
    float* bn = ws;                                        // 128 fp32
    unsigned short* w2b = (unsigned short*)(ws + 128);     // 61440 bf16 (122880 B)
    unsigned short* hst = w2b + 61440;                     // 50000*64 bf16 (6.4 MB)
    unsigned short* sfb = hst + N_PTS * CCH;               // 50000*64 bf16 (6.4 MB)
    unsigned* packG = (unsigned*)(sfb + N_PTS * CCH);      // 50000*32 u32 (6.4 MB)
    int* cntG = (int*)(packG + N_PTS * NH);                // 50000 int (200 KB)

    hipMemsetAsync(bn, 0, 128 * sizeof(float), stream);
    k_prep<<<STATS_BLOCKS + W2P_BLOCKS + CLS_BLOCKS, 256, 0, stream>>>(
        s_feats, W1, W2, q_pts, s_pts, nb, kpts, bn, hst, w2b, sfb, packG, cntG);
    k_main<<<N_PTS / QB, 256, 0, stream>>>(sfb, gamma, beta, bn, b2, w2b, hst,
                                           packG, cntG, out);
}

// Round 11
// 161.160 us; speedup vs baseline: 1.0073x; 1.0073x over previous
//
#include <hip/hip_runtime.h>
#include <hip/hip_bf16.h>
#include <math.h>

#define N_PTS 50000
#define CCH   64
#define KP    15
#define NH    32
#define SIGMA 0.7f
#define BN_EPS 1e-5f
#define LEAKY 0.1f
#define QB    16
#define CWS   18           // cwT row stride in bf16 (16 q + 2 pad -> 2-way banks, free)
#define STATS_BLOCKS 1024
#define W2P_BLOCKS   30
#define QC           64    // queries per classification block
#define CLS_BLOCKS   782   // ceil(50000/64)

typedef short bf16x8 __attribute__((ext_vector_type(8)));
typedef float floatx4 __attribute__((ext_vector_type(4)));

__device__ __forceinline__ unsigned short f2b(float f) {
    union { float f; unsigned u; } v; v.f = f;
    return (unsigned short)((v.u + 0x7FFFu + ((v.u >> 16) & 1u)) >> 16);  // RNE
}
__device__ __forceinline__ ushort2 f2b2(float a, float b) {   // v_cvt_pk_bf16_f32
    __hip_bfloat162 h = __float22bfloat162_rn(float2{a, b});
    union { __hip_bfloat162 h; ushort2 u; } v; v.h = h;
    return v.u;
}
__device__ __forceinline__ float b2f(unsigned short b) {
    union { unsigned u; float f; } v; v.u = ((unsigned)b) << 16;
    return v.f;
}

// ---------- K1: [0,1024) stats: h = sf@W1 -> hst bf16 + BN sums + sfb shadow.
//             [1024,1054) W2 repack.  [1054,1836) neighbor classification. ----------
__global__ __launch_bounds__(256) void k_prep(const float* __restrict__ sf,
                                              const float* __restrict__ W1,
                                              const float* __restrict__ W2,
                                              const float* __restrict__ q_pts,
                                              const float* __restrict__ s_pts,
                                              const int* __restrict__ nb,
                                              const float* __restrict__ kpts,
                                              float* __restrict__ bn,
                                              unsigned short* __restrict__ hst,
                                              unsigned short* __restrict__ w2b,
                                              unsigned short* __restrict__ sfb,
                                              unsigned* __restrict__ packG,
                                              int* __restrict__ cntG) {
    int t = threadIdx.x;
    if (blockIdx.x >= STATS_BLOCKS + W2P_BLOCKS) {
        // ---- neighbor classification, latency-flat version:
        //      batch ALL loads (2 latency exposures), ballot-compact (no LDS,
        //      no atomics, no syncthreads; every query writes a full 32-slot line)
        int q0 = (blockIdx.x - (STATS_BLOCKS + W2P_BLOCKS)) * QC;
        int lane = t & 63, lh = lane & 31;

        // batch 1: 8 neighbor indices (coalesced)
        int idx8[8];
        #pragma unroll
        for (int r = 0; r < 8; ++r) {
            int task = t + r * 256;               // task = ql*32 + hh
            int m = q0 + (task >> 5);
            idx8[r] = (m < N_PTS) ? nb[m * NH + (task & 31)] : 0;
        }
        // batch 2: 24 s_pts gather components + 24 q_pts broadcasts, all in flight
        float sx[8], sy[8], sz[8], qx[8], qy[8], qz[8];
        #pragma unroll
        for (int r = 0; r < 8; ++r) {
            int task = t + r * 256;
            int m = q0 + (task >> 5);
            int mm = (m < N_PTS) ? m : 0;
            sx[r] = s_pts[idx8[r] * 3 + 0];
            sy[r] = s_pts[idx8[r] * 3 + 1];
            sz[r] = s_pts[idx8[r] * 3 + 2];
            qx[r] = q_pts[mm * 3 + 0];            // same addr across half-wave: broadcast
            qy[r] = q_pts[mm * 3 + 1];
            qz[r] = q_pts[mm * 3 + 2];
        }
        float kpr[45];
        #pragma unroll
        for (int i = 0; i < 45; ++i) kpr[i] = kpts[i];   // uniform -> s_loads

        #pragma unroll
        for (int r = 0; r < 8; ++r) {
            int task = t + r * 256;
            int m = q0 + (task >> 5);
            bool valid = (m < N_PTS);
            float px = sx[r] - qx[r], py = sy[r] - qy[r], pz = sz[r] - qz[r];
            float best = 1e30f; int bi = 0;
            #pragma unroll
            for (int k = 0; k < KP; ++k) {
                float dx = px - kpr[k*3], dy = py - kpr[k*3+1], dz = pz - kpr[k*3+2];
                float d = dx * dx + dy * dy + dz * dz;
                if (d < best) { best = d; bi = k; }
            }
            float infl = 1.f - sqrtf(best) * (1.0f / SIGMA);
            bool act = valid && (infl > 0.f);
            unsigned long long bal = __ballot(act);
            unsigned m32 = (unsigned)(bal >> (lane & 32));   // this half-wave's mask
            int prefix = __popc(m32 & ((1u << lh) - 1u));
            int cntq   = __popc(m32);
            int slot   = act ? prefix : cntq + (lh - prefix);
            int iq = (int)(infl * 4095.f + 0.5f);
            unsigned val = act ? ((unsigned)idx8[r] | ((unsigned)bi << 16)
                                  | ((unsigned)iq << 20)) : 0u;
            if (valid) {
                packG[m * NH + slot] = val;       // full 128B line per query
                if (lh == 0) cntG[m] = cntq;
            }
        }
        return;
    }
    if (blockIdx.x >= STATS_BLOCKS) {
        // w2b[((tile*2+kstep)*64+lane)*8+j] = bf16(W2[k][n]),
        //   k = kstep*32 + (lane>>4)*8 + j, n = tile*16 + (lane&15)
        int g = (blockIdx.x - STATS_BLOCKS) * 256 + t;   // 7680 exactly
        int lane = g & 63, s = (g >> 6) & 1, tt = g >> 7;
        int col = lane & 15, quad = lane >> 4;
        int base = (s * 32 + quad * 8) * 960 + tt * 16 + col;
        ushort4 lo, hi;
        lo.x = f2b(W2[base + 0 * 960]); lo.y = f2b(W2[base + 1 * 960]);
        lo.z = f2b(W2[base + 2 * 960]); lo.w = f2b(W2[base + 3 * 960]);
        hi.x = f2b(W2[base + 4 * 960]); hi.y = f2b(W2[base + 5 * 960]);
        hi.z = f2b(W2[base + 6 * 960]); hi.w = f2b(W2[base + 7 * 960]);
        *(ushort4*)(w2b + g * 8)     = lo;
        *(ushort4*)(w2b + g * 8 + 4) = hi;
        return;
    }
    int c = t & 63, ml = t >> 6;
    float w1c[64];
    #pragma unroll
    for (int i = 0; i < 64; ++i) w1c[i] = W1[i * 64 + c];
    __shared__ float rows[4][64];
    float acc_s = 0.f, acc_q = 0.f;
    for (int m0 = blockIdx.x * 4; m0 < N_PTS; m0 += STATS_BLOCKS * 4) {
        __syncthreads();
        float v = sf[m0 * 64 + t];
        ((float*)rows)[t] = v;
        sfb[m0 * 64 + t] = f2b(v);             // bf16 shadow for phase-B gathers
        __syncthreads();
        float h = 0.f;
        #pragma unroll
        for (int i4 = 0; i4 < 16; ++i4) {
            float4 r = *(const float4*)&rows[ml][i4 * 4];
            h += r.x * w1c[i4 * 4] + r.y * w1c[i4 * 4 + 1]
               + r.z * w1c[i4 * 4 + 2] + r.w * w1c[i4 * 4 + 3];
        }
        acc_s += h;
        acc_q += h * h;
        hst[(m0 + ml) * 64 + c] = f2b(h);      // 128B/wave coalesced
    }
    __shared__ float red[2][256];
    red[0][t] = acc_s; red[1][t] = acc_q;
    __syncthreads();
    if (t < 64) {
        float s = red[0][t] + red[0][64 + t] + red[0][128 + t] + red[0][192 + t];
        float q = red[1][t] + red[1][64 + t] + red[1][128 + t] + red[1][192 + t];
        atomicAdd(&bn[t], s);
        atomicAdd(&bn[64 + t], q);
    }
}

// ---------- K2: fused main. 256 threads / 4 waves — the proven round-3 shape. ----------
__global__ __launch_bounds__(256, 4) void k_main(
    const unsigned short* __restrict__ sfb,
    const float* __restrict__ gamma, const float* __restrict__ beta,
    const float* __restrict__ bn, const float* __restrict__ b2,
    const unsigned short* __restrict__ w2b, const unsigned short* __restrict__ hst,
    const unsigned* __restrict__ packG, const int* __restrict__ cntG,
    float* __restrict__ out) {

    __shared__ __align__(16) unsigned short cwT[960 * CWS];  // 34.56 KB: cw[n][q] bf16
    __shared__ float abS[128];                               // BN fold a[64], b[64]

    int t = threadIdx.x;
    int lane = t & 63, wv = t >> 6;
    int m0 = blockIdx.x * QB;

    if (t < 64) {   // inline BN finalize
        float mu  = bn[t] * (1.0f / N_PTS);
        float var = bn[64 + t] * (1.0f / N_PTS) - mu * mu;
        float a   = gamma[t] * rsqrtf(var + BN_EPS);
        abS[t]      = a;
        abS[64 + t] = beta[t] - mu * a;
    }
    __syncthreads();

    // ---- A-fragments directly in registers: fold BN + leaky on bf16 h rows ----
    int row = lane & 15, half = lane >> 4;
    bf16x8 a0, a1;
    {
        const unsigned short* hrow = hst + (m0 + row) * 64 + half * 8;
        bf16x8 r0 = *(const bf16x8*)(hrow);        // c = half*8 + j
        bf16x8 r1 = *(const bf16x8*)(hrow + 32);   // c = 32 + half*8 + j
        #pragma unroll
        for (int j = 0; j < 8; j += 2) {
            int c0 = half * 8 + j;
            float g0 = abS[c0] * b2f((unsigned short)r0[j]) + abS[64 + c0];
            float g1 = abS[c0 + 1] * b2f((unsigned short)r0[j + 1]) + abS[64 + c0 + 1];
            g0 = g0 > 0.f ? g0 : LEAKY * g0;
            g1 = g1 > 0.f ? g1 : LEAKY * g1;
            ushort2 p01 = f2b2(g0, g1);
            a0[j] = (short)p01.x; a0[j + 1] = (short)p01.y;
            int c1 = 32 + c0;
            float g2 = abS[c1] * b2f((unsigned short)r1[j]) + abS[64 + c1];
            float g3 = abS[c1 + 1] * b2f((unsigned short)r1[j + 1]) + abS[64 + c1 + 1];
            g2 = g2 > 0.f ? g2 : LEAKY * g2;
            g3 = g3 > 0.f ? g3 : LEAKY * g3;
            ushort2 p23 = f2b2(g2, g3);
            a1[j] = (short)p23.x; a1[j + 1] = (short)p23.y;
        }
    }

    // ---- phase A: cw = G @ W2 via MFMA; each wave owns 15 n-tiles ----
    {
        int col = lane & 15, quad = lane >> 4;
        for (int ti = 0; ti < 15; ++ti) {
            int tt = wv * 15 + ti;
            bf16x8 bf0 = *(const bf16x8*)(w2b + ((tt * 2 + 0) * 64 + lane) * 8);
            bf16x8 bf1 = *(const bf16x8*)(w2b + ((tt * 2 + 1) * 64 + lane) * 8);
            floatx4 acc = {0.f, 0.f, 0.f, 0.f};
            acc = __builtin_amdgcn_mfma_f32_16x16x32_bf16(a0, bf0, acc, 0, 0, 0);
            acc = __builtin_amdgcn_mfma_f32_16x16x32_bf16(a1, bf1, acc, 0, 0, 0);
            int n = tt * 16 + col;
            float bb = b2[n];
            unsigned short* dst = &cwT[n * CWS + quad * 4];   // D: row(q)=quad*4+reg
            ushort2 w01 = f2b2(acc[0] + bb, acc[1] + bb);     // v_cvt_pk_bf16_f32
            ushort2 w23 = f2b2(acc[2] + bb, acc[3] + bb);
            *(ushort2*)(dst)     = w01;
            *(ushort2*)(dst + 2) = w23;
        }
    }
    __syncthreads();

    // ---- phase B: wave owns 4 queries as 2 pairs; 4-wide interleave.
    //      List reads are wave-uniform (readfirstlane) -> scalar s_loads. ----
    {
        int wvu = __builtin_amdgcn_readfirstlane(wv);
        int c = lane;
        #pragma unroll
        for (int pp = 0; pp < 2; ++pp) {
            int qa = wvu * 4 + pp * 2, qb = qa + 1;
            int ma = m0 + qa, mb = m0 + qb;
            const unsigned* pA = packG + ma * NH;
            const unsigned* pB = packG + mb * NH;
            const unsigned short* cwa = cwT + c * CWS + qa;   // per-lane cw base
            const unsigned short* cwb = cwa + 1;
            int cA = cntG[ma], cB = cntG[mb];                 // uniform -> s_load
            int na = cA > cB ? cA : cB;
            na = (na + 3) & ~3;                               // slots < 32 are zeroed
            float accA = 0.f, accB = 0.f;
            for (int jj = 0; jj < na; jj += 4) {
                unsigned pa0 = pA[jj], pa1 = pA[jj+1], pa2 = pA[jj+2], pa3 = pA[jj+3];
                unsigned pb0 = pB[jj], pb1 = pB[jj+1], pb2 = pB[jj+2], pb3 = pB[jj+3];
                // 8 independent bf16 gathers
                float fA0 = b2f(sfb[(pa0 & 0xFFFFu) * 64 + c]);
                float fA1 = b2f(sfb[(pa1 & 0xFFFFu) * 64 + c]);
                float fA2 = b2f(sfb[(pa2 & 0xFFFFu) * 64 + c]);
                float fA3 = b2f(sfb[(pa3 & 0xFFFFu) * 64 + c]);
                float fB0 = b2f(sfb[(pb0 & 0xFFFFu) * 64 + c]);
                float fB1 = b2f(sfb[(pb1 & 0xFFFFu) * 64 + c]);
                float fB2 = b2f(sfb[(pb2 & 0xFFFFu) * 64 + c]);
                float fB3 = b2f(sfb[(pb3 & 0xFFFFu) * 64 + c]);
                // 8 LDS reads (k*64*CWS offset from scalar field)
                float wA0 = b2f(cwa[((pa0 >> 16) & 15u) * (64 * CWS)]);
                float wA1 = b2f(cwa[((pa1 >> 16) & 15u) * (64 * CWS)]);
                float wA2 = b2f(cwa[((pa2 >> 16) & 15u) * (64 * CWS)]);
                float wA3 = b2f(cwa[((pa3 >> 16) & 15u) * (64 * CWS)]);
                float wB0 = b2f(cwb[((pb0 >> 16) & 15u) * (64 * CWS)]);
                float wB1 = b2f(cwb[((pb1 >> 16) & 15u) * (64 * CWS)]);
                float wB2 = b2f(cwb[((pb2 >> 16) & 15u) * (64 * CWS)]);
                float wB3 = b2f(cwb[((pb3 >> 16) & 15u) * (64 * CWS)]);
                // q12 influence from scalar field
                float iA0 = (float)(pa0 >> 20), iA1 = (float)(pa1 >> 20);
                float iA2 = (float)(pa2 >> 20), iA3 = (float)(pa3 >> 20);
                float iB0 = (float)(pb0 >> 20), iB1 = (float)(pb1 >> 20);
                float iB2 = (float)(pb2 >> 20), iB3 = (float)(pb3 >> 20);
                accA += iA0 * fA0 * wA0 + iA1 * fA1 * wA1
                      + iA2 * fA2 * wA2 + iA3 * fA3 * wA3;
                accB += iB0 * fB0 * wB0 + iB1 * fB1 * wB1
                      + iB2 * fB2 * wB2 + iB3 * fB3 * wB3;
            }
            const float qs = 1.f / 4095.f;
            out[ma * 64 + c] = accA * qs;
            out[mb * 64 + c] = accB * qs;
        }
    }
}

extern "C" void kernel_launch(void* const* d_in, const int* in_sizes, int n_in,
                              void* d_out, int out_size, void* d_ws, size_t ws_size,
                              hipStream_t stream) {
    const float* q_pts   = (const float*)d_in[0];
    const float* s_pts   = (const float*)d_in[1];
    const float* s_feats = (const float*)d_in[2];
    const int*   nb      = (const int*)d_in[3];
    const float* kpts    = (const float*)d_in[4];
    const float* W1      = (const float*)d_in[5];
    const float* gamma   = (const float*)d_in[6];
    const float* beta    = (const float*)d_in[7];
    const float* W2      = (const float*)d_in[8];
    const float* b2      = (const float*)d_in[9];
    float* out = (float*)d_out;

    float* ws = (float*)d_ws;
    float* bn = ws;                                        // 128 fp32
    unsigned short* w2b = (unsigned short*)(ws + 128);     // 61440 bf16 (122880 B)
    unsigned short* hst = w2b + 61440;                     // 50000*64 bf16 (6.4 MB)
    unsigned short* sfb = hst + N_PTS * CCH;               // 50000*64 bf16 (6.4 MB)
    unsigned* packG = (unsigned*)(sfb + N_PTS * CCH);      // 50000*32 u32 (6.4 MB)
    int* cntG = (int*)(packG + N_PTS * NH);                // 50000 int (200 KB)

    hipMemsetAsync(bn, 0, 128 * sizeof(float), stream);
    k_prep<<<STATS_BLOCKS + W2P_BLOCKS + CLS_BLOCKS, 256, 0, stream>>>(
        s_feats, W1, W2, q_pts, s_pts, nb, kpts, bn, hst, w2b, sfb, packG, cntG);
    k_main<<<N_PTS / QB, 256, 0, stream>>>(sfb, gamma, beta, bn, b2, w2b, hst,
                                           packG, cntG, out);
}